// Round 1
// baseline (359.218 us; speedup 1.0000x reference)
//
#include <hip/hip_runtime.h>

// Problem constants (from reference): B=4, N=512, M=512, D=128, H=256, DOUT=128
#define BB    4
#define NN    512
#define MM    512
#define DD    128
#define HH    256
#define DOUTC 128
#define NTILE 8    // n-rows per block in main kernel (L2-reuse of A)
#define MSPLIT 4   // m-chunks per (b, n-tile) for occupancy

// ---------------------------------------------------------------------------
// Kernel 1: precompute
//   A[b,m,h] = sum_d Y[b,m,d] * W1[d,h]                (rows 0..2047 of AC)
//   C[b,n,h] = sum_d X[b,n,d] * W1[D+d,h] + b1[h]      (rows 2048..4095)
// 256 blocks x 256 threads; each block does 16 rows, thread = one h column.
// ---------------------------------------------------------------------------
__global__ __launch_bounds__(256) void precompute_ac(
    const float* __restrict__ X, const float* __restrict__ Y,
    const float* __restrict__ W1, const float* __restrict__ b1,
    float* __restrict__ AC)
{
    __shared__ __align__(16) float rows[16][DD];   // 8 KB
    const int bid = blockIdx.x;        // 0..255
    const int isC = bid >> 7;          // 0: A (from Y), 1: C (from X)
    const int r0  = (bid & 127) * 16;  // global row index (b*512 + m)
    const int t   = threadIdx.x;

    const float* src = isC ? X : Y;
    // stage 16 contiguous rows (2048 floats) into LDS via float4
    const float4* s4 = reinterpret_cast<const float4*>(src + (size_t)r0 * DD);
    float4* l4 = reinterpret_cast<float4*>(&rows[0][0]);
    l4[t]       = s4[t];
    l4[t + 256] = s4[t + 256];
    __syncthreads();

    const int h = t;
    float acc[16];
#pragma unroll
    for (int r = 0; r < 16; ++r) acc[r] = 0.f;

    const float* w = W1 + (isC ? DD * HH : 0) + h;  // column h, coalesced across threads
#pragma unroll
    for (int d = 0; d < DD; d += 4) {
        const float w0 = w[(d + 0) * HH];
        const float w1v = w[(d + 1) * HH];
        const float w2v = w[(d + 2) * HH];
        const float w3v = w[(d + 3) * HH];
#pragma unroll
        for (int r = 0; r < 16; ++r) {
            const float4 yv = *reinterpret_cast<const float4*>(&rows[r][d]);
            acc[r] = fmaf(yv.x, w0, acc[r]);
            acc[r] = fmaf(yv.y, w1v, acc[r]);
            acc[r] = fmaf(yv.z, w2v, acc[r]);
            acc[r] = fmaf(yv.w, w3v, acc[r]);
        }
    }

    const float bias = isC ? b1[h] : 0.f;
#pragma unroll
    for (int r = 0; r < 16; ++r) {
        AC[((size_t)(isC * 2048 + r0 + r)) * HH + h] = acc[r] + bias;
    }
}

// ---------------------------------------------------------------------------
// Kernel 2: main relu-sum (the 268M-element elementwise reduction)
//   part[b,n,ms,h] = sum_{m in chunk ms} relu(A[b,m,h] + C[b,n,h])
// grid = B * (N/NTILE) * MSPLIT = 1024 blocks, 256 threads (thread = h)
// ---------------------------------------------------------------------------
__global__ __launch_bounds__(256) void relu_sum(
    const float* __restrict__ A, const float* __restrict__ C,
    float* __restrict__ part)
{
    const int bid = blockIdx.x;
    const int ms = bid & (MSPLIT - 1);
    const int nt = (bid >> 2) & 63;
    const int b  = bid >> 8;
    const int h  = threadIdx.x;
    const int n0 = nt * NTILE;

    float c[NTILE], acc[NTILE];
#pragma unroll
    for (int i = 0; i < NTILE; ++i) {
        c[i] = C[((size_t)(b * NN + n0 + i)) * HH + h];
        acc[i] = 0.f;
    }

    const float* Ab = A + ((size_t)(b * MM + ms * (MM / MSPLIT))) * HH + h;
#pragma unroll 4
    for (int m = 0; m < MM / MSPLIT; ++m) {
        const float a = Ab[(size_t)m * HH];
#pragma unroll
        for (int i = 0; i < NTILE; ++i)
            acc[i] += fmaxf(a + c[i], 0.f);
    }

#pragma unroll
    for (int i = 0; i < NTILE; ++i)
        part[(((size_t)(b * NN + n0 + i)) * MSPLIT + ms) * HH + h] = acc[i];
}

// ---------------------------------------------------------------------------
// Kernel 3: finalize — reduce MSPLIT partials, apply W2 + M*b2
//   out[b,n,o] = sum_h S[b,n,h]*W2[h,o] + M*b2[o]
// grid = B*N = 2048 blocks, 256 threads
// ---------------------------------------------------------------------------
__global__ __launch_bounds__(256) void finalize(
    const float* __restrict__ part, const float* __restrict__ W2,
    const float* __restrict__ b2, float* __restrict__ out)
{
    __shared__ float S[HH];
    const int bn = blockIdx.x;   // b*512 + n
    const int t  = threadIdx.x;

    float s = 0.f;
#pragma unroll
    for (int ms = 0; ms < MSPLIT; ++ms)
        s += part[((size_t)bn * MSPLIT + ms) * HH + t];
    S[t] = s;
    __syncthreads();

    if (t < DOUTC) {
        float acc = b2[t] * (float)MM;
#pragma unroll 8
        for (int k = 0; k < HH; ++k)
            acc = fmaf(S[k], W2[k * DOUTC + t], acc);
        out[(size_t)bn * DOUTC + t] = acc;
    }
}

// ---------------------------------------------------------------------------
extern "C" void kernel_launch(void* const* d_in, const int* in_sizes, int n_in,
                              void* d_out, int out_size, void* d_ws, size_t ws_size,
                              hipStream_t stream) {
    const float* X  = (const float*)d_in[0];   // [4,512,128]
    const float* Y  = (const float*)d_in[1];   // [4,512,128]
    const float* W1 = (const float*)d_in[2];   // [256,256]
    const float* b1 = (const float*)d_in[3];   // [256]
    const float* W2 = (const float*)d_in[4];   // [256,128]
    const float* b2 = (const float*)d_in[5];   // [128]
    float* out = (float*)d_out;                // [4,512,128]

    float* AC   = (float*)d_ws;                 // 4096*256 f32 = 4 MB
    float* A    = AC;                           // rows 0..2047
    float* C    = AC + 2048 * HH;               // rows 2048..4095
    float* part = AC + 4096 * HH;               // 4*512*4*256 f32 = 8 MB

    hipLaunchKernelGGL(precompute_ac, dim3(256), dim3(256), 0, stream,
                       X, Y, W1, b1, AC);
    hipLaunchKernelGGL(relu_sum, dim3(BB * (NN / NTILE) * MSPLIT), dim3(256), 0, stream,
                       A, C, part);
    hipLaunchKernelGGL(finalize, dim3(BB * NN), dim3(256), 0, stream,
                       part, W2, b2, out);
}

// Round 2
// 51.115 us; speedup vs baseline: 7.0276x; 7.0276x over previous
//
#include <hip/hip_runtime.h>

// Problem constants (from reference): B=4, N=512, M=512, D=128, H=256, DOUT=128
#define BB    4
#define NN    512
#define MM    512
#define DD    128
#define HH    256
#define DOUTC 128
#define NTILE 8    // n-rows per relu_sum block
#define MSPLIT 4   // m-chunks per (b, n-tile)

typedef float v2f __attribute__((ext_vector_type(2)));

// ---------------------------------------------------------------------------
// Kernel 1: precompute
//   A[b,m,h] = sum_d Y[b,m,d] * W1[d,h]                (rows 0..2047 of AC)
//   C[b,n,h] = sum_d X[b,n,d] * W1[D+d,h] + b1[h]      (rows 2048..4095)
// 512 blocks x 256 threads; each block does 8 rows, thread = one h column.
// NOTE: unroll capped at 2 — full unroll hoisted all 128 W1 loads last round
// (VGPR=256, 432MB scratch spill, 320us).
// ---------------------------------------------------------------------------
__global__ __launch_bounds__(256) void precompute_ac(
    const float* __restrict__ X, const float* __restrict__ Y,
    const float* __restrict__ W1, const float* __restrict__ b1,
    float* __restrict__ AC)
{
    __shared__ __align__(16) float rows[8][DD];   // 4 KB
    const int bid = blockIdx.x;        // 0..511
    const int isC = bid >> 8;          // 0: A (from Y), 1: C (from X)
    const int r0  = (bid & 255) * 8;   // global row index (b*512 + m)
    const int t   = threadIdx.x;

    const float* src = isC ? X : Y;
    // stage 8 contiguous rows (1024 floats = 256 float4) into LDS
    const float4* s4 = reinterpret_cast<const float4*>(src + (size_t)r0 * DD);
    reinterpret_cast<float4*>(&rows[0][0])[t] = s4[t];
    __syncthreads();

    const int h = t;
    float acc[8];
#pragma unroll
    for (int r = 0; r < 8; ++r) acc[r] = 0.f;

    const float* wp = W1 + (isC ? DD * HH : 0) + h;  // column h, coalesced
#pragma unroll 2
    for (int d = 0; d < DD; d += 4) {
        const float w0 = wp[(d + 0) * HH];
        const float w1v = wp[(d + 1) * HH];
        const float w2v = wp[(d + 2) * HH];
        const float w3v = wp[(d + 3) * HH];
#pragma unroll
        for (int r = 0; r < 8; ++r) {
            const float4 rv = *reinterpret_cast<const float4*>(&rows[r][d]);
            acc[r] = fmaf(rv.x, w0, acc[r]);
            acc[r] = fmaf(rv.y, w1v, acc[r]);
            acc[r] = fmaf(rv.z, w2v, acc[r]);
            acc[r] = fmaf(rv.w, w3v, acc[r]);
        }
    }

    const float bias = isC ? b1[h] : 0.f;
#pragma unroll
    for (int r = 0; r < 8; ++r) {
        AC[((size_t)(isC * 2048 + r0 + r)) * HH + h] = acc[r] + bias;
    }
}

// ---------------------------------------------------------------------------
// Kernel 2: main relu-sum (268M-element pairwise reduce, VALU-bound)
//   part[b,n,ms,h] = sum_{m in chunk ms} relu(A[b,m,h] + C[b,n,h])
// grid = B * (N/NTILE) * MSPLIT = 1024 blocks, 256 threads.
// Thread = (h-pair, n-half): hp = t&127 -> h0 = 2*hp; nh = t>>7 -> 4 rows.
// float2 arithmetic so compiler can emit v_pk_add_f32 (max stays scalar).
// ---------------------------------------------------------------------------
__global__ __launch_bounds__(256) void relu_sum(
    const float* __restrict__ A, const float* __restrict__ C,
    float* __restrict__ part)
{
    const int bid = blockIdx.x;
    const int ms = bid & (MSPLIT - 1);
    const int nt = (bid >> 2) & 63;
    const int b  = bid >> 8;
    const int t  = threadIdx.x;
    const int hp = t & 127;
    const int h0 = hp * 2;
    const int nh = t >> 7;
    const int n0 = nt * NTILE + nh * 4;

    v2f c[4], acc[4];
#pragma unroll
    for (int i = 0; i < 4; ++i) {
        c[i] = *reinterpret_cast<const v2f*>(&C[((size_t)(b * NN + n0 + i)) * HH + h0]);
        acc[i] = (v2f){0.f, 0.f};
    }

    const float* Ab = A + ((size_t)(b * MM + ms * (MM / MSPLIT))) * HH + h0;
#pragma unroll 4
    for (int m = 0; m < MM / MSPLIT; ++m) {
        const v2f a2 = *reinterpret_cast<const v2f*>(&Ab[(size_t)m * HH]);
#pragma unroll
        for (int i = 0; i < 4; ++i) {
            v2f s = a2 + c[i];              // v_pk_add_f32
            s.x = fmaxf(s.x, 0.f);
            s.y = fmaxf(s.y, 0.f);
            acc[i] += s;                    // v_pk_add_f32
        }
    }

#pragma unroll
    for (int i = 0; i < 4; ++i)
        *reinterpret_cast<v2f*>(
            &part[(((size_t)(b * NN + n0 + i)) * MSPLIT + ms) * HH + h0]) = acc[i];
}

// ---------------------------------------------------------------------------
// Kernel 3: finalize — reduce MSPLIT partials, apply W2 + M*b2
//   out[bn,o] = sum_h S[bn,h]*W2[h,o] + M*b2[o]
// 8 bn-rows per block (amortizes W2 L2 traffic 8x). 256 blocks x 256 threads.
// Threads: o = t&127 output col, rhalf = t>>7 -> 4 rows each.
// ---------------------------------------------------------------------------
__global__ __launch_bounds__(256) void finalize(
    const float* __restrict__ part, const float* __restrict__ W2,
    const float* __restrict__ b2, float* __restrict__ out)
{
    __shared__ __align__(16) float S[8][HH];   // 8 KB
    const int bn0 = blockIdx.x * 8;
    const int t   = threadIdx.x;

    // stage 1: reduce partials into S
#pragma unroll
    for (int r = 0; r < 8; ++r) {
        float s = 0.f;
#pragma unroll
        for (int ms = 0; ms < MSPLIT; ++ms)
            s += part[((size_t)(bn0 + r) * MSPLIT + ms) * HH + t];
        S[r][t] = s;
    }
    __syncthreads();

    const int o     = t & 127;
    const int rbase = (t >> 7) * 4;

    float acc[4];
    const float binit = b2[o] * (float)MM;
#pragma unroll
    for (int j = 0; j < 4; ++j) acc[j] = binit;

    const float* w2p = W2 + o;
#pragma unroll 2
    for (int k = 0; k < HH; k += 4) {
        const float w0 = w2p[(k + 0) * DOUTC];
        const float w1v = w2p[(k + 1) * DOUTC];
        const float w2v = w2p[(k + 2) * DOUTC];
        const float w3v = w2p[(k + 3) * DOUTC];
#pragma unroll
        for (int j = 0; j < 4; ++j) {
            const float4 sv = *reinterpret_cast<const float4*>(&S[rbase + j][k]);
            acc[j] = fmaf(sv.x, w0, acc[j]);
            acc[j] = fmaf(sv.y, w1v, acc[j]);
            acc[j] = fmaf(sv.z, w2v, acc[j]);
            acc[j] = fmaf(sv.w, w3v, acc[j]);
        }
    }

#pragma unroll
    for (int j = 0; j < 4; ++j)
        out[(size_t)(bn0 + rbase + j) * DOUTC + o] = acc[j];
}

// ---------------------------------------------------------------------------
extern "C" void kernel_launch(void* const* d_in, const int* in_sizes, int n_in,
                              void* d_out, int out_size, void* d_ws, size_t ws_size,
                              hipStream_t stream) {
    const float* X  = (const float*)d_in[0];   // [4,512,128]
    const float* Y  = (const float*)d_in[1];   // [4,512,128]
    const float* W1 = (const float*)d_in[2];   // [256,256]
    const float* b1 = (const float*)d_in[3];   // [256]
    const float* W2 = (const float*)d_in[4];   // [256,128]
    const float* b2 = (const float*)d_in[5];   // [128]
    float* out = (float*)d_out;                // [4,512,128]

    float* AC   = (float*)d_ws;                 // 4096*256 f32 = 4 MB
    float* A    = AC;                           // rows 0..2047
    float* C    = AC + 2048 * HH;               // rows 2048..4095
    float* part = AC + 4096 * HH;               // 4*512*4*256 f32 = 8 MB

    hipLaunchKernelGGL(precompute_ac, dim3(512), dim3(256), 0, stream,
                       X, Y, W1, b1, AC);
    hipLaunchKernelGGL(relu_sum, dim3(BB * (NN / NTILE) * MSPLIT), dim3(256), 0, stream,
                       A, C, part);
    hipLaunchKernelGGL(finalize, dim3(BB * NN / 8), dim3(256), 0, stream,
                       part, W2, b2, out);
}